// Round 4
// baseline (579.065 us; speedup 1.0000x reference)
//
#include <hip/hip_runtime.h>
#include <stdint.h>

typedef unsigned short u16;
typedef short bf16x8 __attribute__((ext_vector_type(8)));
typedef float f32x4 __attribute__((ext_vector_type(4)));

#define MFMA16(a, b, c) __builtin_amdgcn_mfma_f32_16x16x32_bf16((a), (b), (c), 0, 0, 0)

static __device__ __forceinline__ float bfu2f(u16 u) {
  union { unsigned int i; float f; } z; z.i = ((unsigned int)u) << 16; return z.f;
}
static __device__ __forceinline__ u16 f2bfu(float f) {
  union { float f; unsigned int i; } z; z.f = f;
  unsigned int i = z.i;
  return (u16)((i + 0x7fffu + ((i >> 16) & 1u)) >> 16);
}

__device__ __forceinline__ void gload_lds16(const void* g, void* l) {
  __builtin_amdgcn_global_load_lds((const __attribute__((address_space(1))) void*)g,
                                   (__attribute__((address_space(3))) void*)l, 16, 0, 0);
}

// ---------------------------------------------------------------- LayerNorm
__global__ __launch_bounds__(256) void ln_kernel(
    const float* __restrict__ x, const float* __restrict__ w,
    const float* __restrict__ b, u16* __restrict__ xn) {
  int row = blockIdx.x;
  int t = threadIdx.x;
  const float4* xr = (const float4*)(x + (size_t)row * 1024);
  float4 v = xr[t];
  float s = v.x + v.y + v.z + v.w;
  float ss = v.x * v.x + v.y * v.y + v.z * v.z + v.w * v.w;
#pragma unroll
  for (int m = 1; m < 64; m <<= 1) { s += __shfl_xor(s, m); ss += __shfl_xor(ss, m); }
  __shared__ float sb[4], ssb[4];
  int lane = t & 63, wvi = t >> 6;
  if (lane == 0) { sb[wvi] = s; ssb[wvi] = ss; }
  __syncthreads();
  s = sb[0] + sb[1] + sb[2] + sb[3];
  ss = ssb[0] + ssb[1] + ssb[2] + ssb[3];
  float mu = s * (1.0f / 1024.0f);
  float var = ss * (1.0f / 1024.0f) - mu * mu;
  float rstd = rsqrtf(var + 1e-5f);
  float4 wv4 = ((const float4*)w)[t];
  float4 bv4 = ((const float4*)b)[t];
  ushort4 o;
  o.x = f2bfu((v.x - mu) * rstd * wv4.x + bv4.x);
  o.y = f2bfu((v.y - mu) * rstd * wv4.y + bv4.y);
  o.z = f2bfu((v.z - mu) * rstd * wv4.z + bv4.z);
  o.w = f2bfu((v.w - mu) * rstd * wv4.w + bv4.w);
  ((ushort4*)xn)[(size_t)row * 256 + t] = o;
}

// ------------------------------------------------------------- f32 -> bf16
__global__ void cvt3_kernel(const float* __restrict__ a, u16* __restrict__ oa, int na,
                            const float* __restrict__ b, u16* __restrict__ ob, int nb,
                            const float* __restrict__ c, u16* __restrict__ oc, int nc) {
  int total = (na + nb + nc) >> 2;
  for (int i = blockIdx.x * blockDim.x + threadIdx.x; i < total; i += gridDim.x * blockDim.x) {
    int j = i << 2;
    const float* s; u16* d; int off;
    if (j < na) { s = a; d = oa; off = j; }
    else if (j < na + nb) { s = b; d = ob; off = j - na; }
    else { s = c; d = oc; off = j - na - nb; }
    float4 v = *(const float4*)(s + off);
    ushort4 o;
    o.x = f2bfu(v.x); o.y = f2bfu(v.y); o.z = f2bfu(v.z); o.w = f2bfu(v.w);
    *(ushort4*)(d + off) = o;
  }
}

// --------------------------------------------------- GEMM  C = A @ Bw^T + bias
// m201-style 8-phase schedule: BM=BN=256, BK=64, 8 waves (2Mx4N), per-wave
// 128x64 output. 2 double-buffered LDS K-tiles; 4 quadrant-phases per K-tile;
// counted vmcnt(6) once per K-tile. Bijective XCD swizzle on flattened block
// index (requires gridDim.x*gridDim.y % 8 == 0 -- true for all our grids).
// MODE 0: bf16 out; MODE 1: f32 out; MODE 2: qkv scatter (V stored transposed).
template <int MODE>
__global__ __launch_bounds__(512, 2) void gemm_bt(
    const u16* __restrict__ A, const u16* __restrict__ Bw,
    const float* __restrict__ bias,
    float* __restrict__ Cf, u16* __restrict__ Cb,
    u16* __restrict__ Qo, u16* __restrict__ Ko, u16* __restrict__ Vo,
    int M, int N, int K) {
  __shared__ __attribute__((aligned(16))) u16 As[2][16384];  // [256][64] bf16
  __shared__ __attribute__((aligned(16))) u16 Bs[2][16384];  // [256][64] bf16
  int tid = threadIdx.x;
  int lane = tid & 63;
  int w = tid >> 6;            // 0..7
  int wr = w >> 2, wc = w & 3; // wave grid 2 (M) x 4 (N)
  int r16 = lane & 15, hi = lane >> 4;
  int l8 = lane >> 3, li = lane & 7;

  // XCD-aware bijective swizzle (nwg % 8 == 0).
  int nwg = gridDim.x * gridDim.y;
  int flat = blockIdx.y * gridDim.x + blockIdx.x;
  int q8 = nwg >> 3;
  int swz = (flat & 7) * q8 + (flat >> 3);
  int bx = swz % gridDim.x, by = swz / gridDim.x;

  const char* Abase = (const char*)(A + (size_t)by * 256 * K);
  const char* Bbase = (const char*)(Bw + (size_t)bx * 256 * K);
  size_t rowbytes = (size_t)K * 2;
  int colsw = (li ^ l8) << 4;  // pre-swizzled source 16B slot in 128B window
  int nkt = K >> 6;            // assumed >= 2

  f32x4 z4 = {0.f, 0.f, 0.f, 0.f};
  f32x4 acc[8][4];
#pragma unroll
  for (int m = 0; m < 8; ++m)
#pragma unroll
    for (int n = 0; n < 4; ++n) acc[m][n] = z4;

  // One 8KB stage block: 64 LDS rows; wave w covers rows r0+w*8+l8.
#define SG_A(buf, t, r0)                                                      \
  gload_lds16(Abase + (size_t)((r0) + w * 8 + l8) * rowbytes + ((t) << 7) +   \
                  colsw,                                                      \
              (char*)As[buf] + ((r0) + w * 8) * 128)
#define SG_B(buf, t, r0)                                                      \
  gload_lds16(Bbase + (size_t)((r0) + w * 8 + l8) * rowbytes + ((t) << 7) +   \
                  colsw,                                                      \
              (char*)Bs[buf] + ((r0) + w * 8) * 128)

  // Prologue: tile0 full (8 issues) + tile1 first 6 issues.
  SG_A(0, 0, 0); SG_A(0, 0, 64); SG_A(0, 0, 128); SG_A(0, 0, 192);
  SG_B(0, 0, 0); SG_B(0, 0, 64); SG_B(0, 0, 128); SG_B(0, 0, 192);
  SG_A(1, 1, 0); SG_A(1, 1, 128); SG_B(1, 1, 0); SG_B(1, 1, 64);
  SG_A(1, 1, 64); SG_A(1, 1, 192);
  asm volatile("s_waitcnt vmcnt(6)" ::: "memory");
  __builtin_amdgcn_s_barrier();
  __builtin_amdgcn_sched_barrier(0);

  int buf = 0;
  bf16x8 af[4][2], bfr[4][2];

#define LDA(mh)                                                               \
  _Pragma("unroll") for (int m = 0; m < 4; ++m) {                             \
    int row = wr * 128 + (mh) * 64 + m * 16 + r16;                            \
    int sw = (row & 7) << 4;                                                  \
    _Pragma("unroll") for (int kk = 0; kk < 2; ++kk)                          \
        af[m][kk] = *(const bf16x8*)(ab + row * 128 +                         \
                                     (((kk << 6) | (hi << 4)) ^ sw));         \
  }
#define LDB(nh)                                                               \
  _Pragma("unroll") for (int n = 0; n < 2; ++n) {                             \
    int row = wc * 64 + (nh) * 32 + n * 16 + r16;                             \
    int sw = (row & 7) << 4;                                                  \
    _Pragma("unroll") for (int kk = 0; kk < 2; ++kk)                          \
        bfr[(nh) * 2 + n][kk] = *(const bf16x8*)(ab2 + row * 128 +            \
                                     (((kk << 6) | (hi << 4)) ^ sw));         \
  }
#define MM(mh, nh)                                                            \
  __builtin_amdgcn_s_setprio(1);                                              \
  _Pragma("unroll") for (int kk = 0; kk < 2; ++kk)                            \
      _Pragma("unroll") for (int m = 0; m < 4; ++m)                           \
          _Pragma("unroll") for (int n = 0; n < 2; ++n)                       \
              acc[(mh) * 4 + m][(nh) * 2 + n] =                               \
      MFMA16(af[m][kk], bfr[(nh) * 2 + n][kk], acc[(mh) * 4 + m][(nh) * 2 + n]); \
  __builtin_amdgcn_s_setprio(0)

#define BAR1                                                                  \
  __builtin_amdgcn_s_barrier();                                               \
  __builtin_amdgcn_sched_barrier(0)
#define BAR2                                                                  \
  __builtin_amdgcn_sched_barrier(0);                                          \
  __builtin_amdgcn_s_barrier();                                               \
  __builtin_amdgcn_sched_barrier(0)

  for (int t = 0; t < nkt; ++t) {
    const char* ab = (const char*)As[buf];
    const char* ab2 = (const char*)Bs[buf];
    bool s1 = (t + 1 < nkt), s2 = (t + 2 < nkt);
    // ---- phase q0: quadrant (mh0, nh0)
    LDA(0);
    LDB(0);
    if (s1) { SG_B(buf ^ 1, t + 1, 128); SG_B(buf ^ 1, t + 1, 192); }
    BAR1;
    MM(0, 0);
    BAR2;
    // ---- phase q1: (mh0, nh1)
    LDB(1);
    if (s2) { SG_A(buf, t + 2, 0); SG_A(buf, t + 2, 128); }
    BAR1;
    MM(0, 1);
    BAR2;
    // ---- phase q2: (mh1, nh0)
    LDA(1);
    if (s2) { SG_B(buf, t + 2, 0); SG_B(buf, t + 2, 64); }
    BAR1;
    MM(1, 0);
    BAR2;
    // ---- phase q3: (mh1, nh1)  (frags already in regs)
    if (s2) { SG_A(buf, t + 2, 64); SG_A(buf, t + 2, 192); }
    BAR1;
    MM(1, 1);
    __builtin_amdgcn_sched_barrier(0);
    if (s2) {
      asm volatile("s_waitcnt vmcnt(6)" ::: "memory");
    } else {
      asm volatile("s_waitcnt vmcnt(0)" ::: "memory");
    }
    __builtin_amdgcn_s_barrier();
    __builtin_amdgcn_sched_barrier(0);
    buf ^= 1;
  }
#undef SG_A
#undef SG_B
#undef LDA
#undef LDB
#undef MM
#undef BAR1
#undef BAR2

#pragma unroll
  for (int m = 0; m < 8; ++m)
#pragma unroll
    for (int n = 0; n < 4; ++n) {
      int row0 = by * 256 + wr * 128 + m * 16 + hi * 4;
      int col = bx * 256 + wc * 64 + n * 16 + r16;
      if (MODE == 2) {
        int jt = col >> 10;
        int h = (col >> 6) & 15, dh = col & 63;
        int bb = row0 >> 12, nt0 = row0 & 4095;
        float bcol = bias[col];
        if (jt == 2) {
          // V stored transposed: VT[bh][dh][n] -> vectorized ushort4 store.
          ushort4 o;
          o.x = f2bfu(acc[m][n][0] + bcol);
          o.y = f2bfu(acc[m][n][1] + bcol);
          o.z = f2bfu(acc[m][n][2] + bcol);
          o.w = f2bfu(acc[m][n][3] + bcol);
          *(ushort4*)&Vo[(((size_t)bb * 16 + h) * 64 + dh) * 4096 + nt0] = o;
        } else {
          u16* dst = (jt == 0) ? Qo : Ko;
#pragma unroll
          for (int r = 0; r < 4; ++r)
            dst[(((size_t)bb * 16 + h) * 4096 + nt0 + r) * 64 + dh] =
                f2bfu(acc[m][n][r] + bcol);
        }
      } else {
        float bcol = bias[col];
#pragma unroll
        for (int r = 0; r < 4; ++r) {
          int row = row0 + r;
          float val = acc[m][n][r] + bcol;
          if (MODE == 0) Cb[(size_t)row * N + col] = f2bfu(val);
          else           Cf[(size_t)row * N + col] = val;
        }
      }
    }
}

// ------------------------------------------------------------- landmarks
__global__ __launch_bounds__(64) void landmark_kernel(
    const u16* __restrict__ Q, const u16* __restrict__ K,
    float* __restrict__ qlmf, u16* __restrict__ qlmb,
    float* __restrict__ klmf, u16* __restrict__ klmb) {
  int bm = blockIdx.x;  // bh*64 + m
  int bh = bm >> 6, m = bm & 63;
  int d = threadIdx.x;
  const u16* src = blockIdx.y ? K : Q;
  const u16* p = src + (((size_t)bh * 4096) + m * 64) * 64 + d;
  float s = 0.f;
#pragma unroll 8
  for (int r = 0; r < 64; ++r) s += bfu2f(p[(size_t)r * 64]);
  float val = s * (0.25f / 64.0f);  // mean * SCALE
  size_t o = (size_t)bh * 4096 + m * 64 + d;
  if (blockIdx.y) { klmf[o] = val; klmb[o] = f2bfu(val); }
  else            { qlmf[o] = val; qlmb[o] = f2bfu(val); }
}

// ---------------------- attn3 scores + exp + (E @ V^T-layout) partials
__global__ __launch_bounds__(256) void attn3_pv_kernel(
    const u16* __restrict__ qlmb, const u16* __restrict__ Kmat,
    const u16* __restrict__ Vt, float* __restrict__ Upart,
    float* __restrict__ rspart) {
  __shared__ __attribute__((aligned(16))) u16 Elds[4][8192];  // per-wave 64x128 bf16, swizzled
  int chunk = blockIdx.x, bh = blockIdx.y;
  int tid = threadIdx.x, lane = tid & 63, w = tid >> 6;
  int r16 = lane & 15, hi = lane >> 4;
  int keybase = chunk * 512 + w * 128;
  const u16* kb = Kmat + ((size_t)bh * 4096 + keybase) * 64;
  const u16* vtb = Vt + (size_t)bh * 262144;  // V^T: [64][4096] per bh
  const u16* qb = qlmb + (size_t)bh * 4096;
  u16* eb = &Elds[w][0];
  f32x4 z4 = {0.f, 0.f, 0.f, 0.f};

  bf16x8 afr[4][2];
#pragma unroll
  for (int m = 0; m < 4; ++m)
#pragma unroll
    for (int kk = 0; kk < 2; ++kk)
      afr[m][kk] = *(const bf16x8*)(qb + (m * 16 + r16) * 64 + kk * 32 + hi * 8);

  float rs[4][4] = {};
  for (int cf = 0; cf < 8; ++cf) {
    f32x4 S[4] = {z4, z4, z4, z4};
#pragma unroll
    for (int kk = 0; kk < 2; ++kk) {
      bf16x8 bfr = *(const bf16x8*)(kb + (size_t)(cf * 16 + r16) * 64 + kk * 32 + hi * 8);
#pragma unroll
      for (int m = 0; m < 4; ++m) S[m] = MFMA16(afr[m][kk], bfr, S[m]);
    }
#pragma unroll
    for (int m = 0; m < 4; ++m)
#pragma unroll
      for (int r = 0; r < 4; ++r) {
        float e = __expf(S[m][r]);  // max-free: logits are O(0.1) by construction
        rs[m][r] += e;
        int row = m * 16 + hi * 4 + r;
        int key = cf * 16 + r16;
        *(u16*)((char*)eb + row * 256 + ((key * 2) ^ ((row & 7) << 4))) = f2bfu(e);
      }
  }
#pragma unroll
  for (int m = 0; m < 4; ++m)
#pragma unroll
    for (int r = 0; r < 4; ++r) {
      float v = rs[m][r];
      v += __shfl_xor(v, 1); v += __shfl_xor(v, 2);
      v += __shfl_xor(v, 4); v += __shfl_xor(v, 8);
      rs[m][r] = v;
    }
  if (r16 == 0) {
    float* rp = rspart + (((size_t)bh * 8 + chunk) * 4 + w) * 64;
#pragma unroll
    for (int m = 0; m < 4; ++m)
#pragma unroll
      for (int r = 0; r < 4; ++r) rp[m * 16 + hi * 4 + r] = rs[m][r];
  }
  __syncthreads();

  f32x4 U[4][4];
#pragma unroll
  for (int m = 0; m < 4; ++m)
#pragma unroll
    for (int df = 0; df < 4; ++df) U[m][df] = z4;
  for (int ks = 0; ks < 4; ++ks) {
    bf16x8 ea[4];
#pragma unroll
    for (int m = 0; m < 4; ++m) {
      int row = m * 16 + r16;
      ea[m] = *(const bf16x8*)((char*)eb + row * 256 + (((ks * 32 + hi * 8) * 2) ^ ((row & 7) << 4)));
    }
#pragma unroll
    for (int df = 0; df < 4; ++df) {
      bf16x8 vb8 = *(const bf16x8*)(vtb + (size_t)(df * 16 + r16) * 4096 +
                                    keybase + ks * 32 + hi * 8);
#pragma unroll
      for (int m = 0; m < 4; ++m) U[m][df] = MFMA16(ea[m], vb8, U[m][df]);
    }
  }
  float* up = Upart + (((size_t)bh * 8 + chunk) * 4 + w) * 4096;
#pragma unroll
  for (int m = 0; m < 4; ++m)
#pragma unroll
    for (int df = 0; df < 4; ++df)
#pragma unroll
      for (int r = 0; r < 4; ++r)
        up[(m * 16 + hi * 4 + r) * 64 + df * 16 + r16] = U[m][df][r];
}

// ------------- combine partials, attn2 softmax, Newton-Schulz (fp32), W = A2inv @ T
// 512 threads: mm64 thread grid 32x16, 2x4 per thread.
__device__ __forceinline__ void mm64(const float (*AT)[68], const float (*Bm)[68],
                                     float (*C)[68], float (*CT)[68],
                                     float alpha, int tid) {
  int tr = (tid >> 4) << 1;
  int tc = (tid & 15) << 2;
  float acc[2][4] = {};
  for (int k = 0; k < 64; ++k) {
    float2 av = *(const float2*)&AT[k][tr];
    float4 bv = *(const float4*)&Bm[k][tc];
    float aa[2] = {av.x, av.y};
    float bb[4] = {bv.x, bv.y, bv.z, bv.w};
#pragma unroll
    for (int i = 0; i < 2; ++i)
#pragma unroll
      for (int j = 0; j < 4; ++j) acc[i][j] = fmaf(aa[i], bb[j], acc[i][j]);
  }
#pragma unroll
  for (int i = 0; i < 2; ++i)
#pragma unroll
    for (int j = 0; j < 4; ++j) {
      float vv = acc[i][j] * alpha;
      C[tr + i][tc + j] = vv;
      if (CT) CT[tc + j][tr + i] = vv;
    }
}

__global__ __launch_bounds__(512) void combine_ns_kernel(
    const float* __restrict__ Upart, const float* __restrict__ rspart,
    const float* __restrict__ qlmf, const float* __restrict__ klmf,
    u16* __restrict__ WT) {
  __shared__ __attribute__((aligned(16))) float A2T[64][68];
  __shared__ __attribute__((aligned(16))) float Vv[64][68];
  __shared__ __attribute__((aligned(16))) float VT[64][68];
  __shared__ __attribute__((aligned(16))) float KV[64][68];
  __shared__ __attribute__((aligned(16))) float KVT[64][68];
  __shared__ __attribute__((aligned(16))) float T2[64][68];
  __shared__ __attribute__((aligned(16))) float T4[64][68];
  __shared__ __attribute__((aligned(16))) float Tm[64][68];
  __shared__ float rsum[64], redbuf[64];
  __shared__ float v0s, scal;
  int bh = blockIdx.x, tid = threadIdx.x;

  if (tid < 64) {
    float s = 0.f;
    const float* rp = rspart + (size_t)bh * 32 * 64 + tid;
    for (int p = 0; p < 32; ++p) s += rp[p * 64];
    rsum[tid] = s;
  }
  __syncthreads();
  for (int idx = tid; idx < 4096; idx += 512) {
    float s = 0.f;
    const float* up = Upart + (size_t)bh * 32 * 4096 + idx;
    for (int p = 0; p < 32; ++p) s += up[(size_t)p * 4096];
    int r = idx >> 6, c = idx & 63;
    Tm[r][c] = s / rsum[r];  // T = attn3 @ v (row-normalized)
  }
  for (int idx = tid; idx < 4096; idx += 512) {
    int r = idx >> 6, c = idx & 63;
    Vv[c][r] = qlmf[(size_t)bh * 4096 + idx];  // qlm^T
    VT[c][r] = klmf[(size_t)bh * 4096 + idx];  // klm^T
  }
  __syncthreads();
  mm64(&Vv[0], &VT[0], &T2[0], nullptr, 1.0f, tid);  // S2 = qlm @ klm^T
  __syncthreads();
  if (tid < 64) {  // softmax row tid (fp32)
    float mx = -1e30f;
    for (int c2 = 0; c2 < 64; ++c2) mx = fmaxf(mx, T2[tid][c2]);
    float s = 0.f;
    for (int c2 = 0; c2 < 64; ++c2) { float e = __expf(T2[tid][c2] - mx); T2[tid][c2] = e; s += e; }
    float inv = 1.f / s;
    for (int c2 = 0; c2 < 64; ++c2) { float p = T2[tid][c2] * inv; T2[tid][c2] = p; A2T[c2][tid] = p; }
  }
  __syncthreads();
  if (tid < 64) {  // column sums of |A2|
    float cs = 0.f;
    for (int r2 = 0; r2 < 64; ++r2) cs += fabsf(T2[r2][tid]);
    redbuf[tid] = cs;
  }
  __syncthreads();
  if (tid == 0) {
    float v0 = 0.f;
    for (int c2 = 0; c2 < 64; ++c2) v0 = fmaxf(v0, redbuf[c2]);
    v0s = v0;
  }
  __syncthreads();
  if (tid < 64) {  // row sums
    float rs2 = 0.f;
    for (int c2 = 0; c2 < 64; ++c2) rs2 += fabsf(T2[tid][c2]);
    redbuf[tid] = rs2;
  }
  __syncthreads();
  if (tid == 0) {
    float vi = 0.f;
    for (int r2 = 0; r2 < 64; ++r2) vi = fmaxf(vi, redbuf[r2]);
    scal = 1.0f / (v0s * vi);
  }
  __syncthreads();
  for (int idx = tid; idx < 4096; idx += 512) {
    int r = idx >> 6, c = idx & 63;
    Vv[r][c] = A2T[r][c] * scal;  // V = A2^T / (V0*VI)
    VT[r][c] = T2[r][c] * scal;   // V^T
  }
  __syncthreads();
  for (int it = 0; it < 6; ++it) {
    mm64(&A2T[0], &Vv[0], &KV[0], &KVT[0], 1.0f, tid);  // KV = A2 @ V
    __syncthreads();
    for (int idx = tid; idx < 4096; idx += 512) {
      int r = idx >> 6, c = idx & 63;
      T2[r][c] = ((r == c) ? 7.0f : 0.0f) - KV[r][c];
    }
    __syncthreads();
    mm64(&KVT[0], &T2[0], &T4[0], nullptr, 1.0f, tid);  // KV @ (7I - KV)
    __syncthreads();
    for (int idx = tid; idx < 4096; idx += 512) {
      int r = idx >> 6, c = idx & 63;
      T2[r][c] = ((r == c) ? 15.0f : 0.0f) - T4[r][c];
    }
    __syncthreads();
    mm64(&KVT[0], &T2[0], &T4[0], nullptr, 1.0f, tid);  // KV @ (15I - ...)
    __syncthreads();
    for (int idx = tid; idx < 4096; idx += 512) {
      int r = idx >> 6, c = idx & 63;
      T2[r][c] = ((r == c) ? 13.0f : 0.0f) - T4[r][c];
    }
    __syncthreads();
    mm64(&VT[0], &T2[0], &T4[0], nullptr, 0.25f, tid);  // Vnew = 0.25 V @ (13I - ...)
    __syncthreads();
    for (int idx = tid; idx < 4096; idx += 512) {
      int r = idx >> 6, c = idx & 63;
      float vvv = T4[r][c];
      Vv[r][c] = vvv; VT[c][r] = vvv;
    }
    __syncthreads();
  }
  mm64(&VT[0], &Tm[0], &T2[0], nullptr, 1.0f, tid);  // W = A2inv @ T
  __syncthreads();
  for (int idx = tid; idx < 4096; idx += 512) {
    int r = idx >> 6, c = idx & 63;
    WT[(size_t)bh * 4096 + c * 64 + r] = f2bfu(T2[r][c]);  // store W^T bf16
  }
}

// ------------------- final: softmax(q @ klm^T) @ W  ->  attn_out (B,N,C) bf16
__global__ __launch_bounds__(256) void attn1_out_kernel(
    const u16* __restrict__ Q, const u16* __restrict__ klmb,
    const u16* __restrict__ WT, u16* __restrict__ AO) {
  __shared__ __attribute__((aligned(16))) u16 Elds[4][2048];  // per-wave 32x64 bf16
  int bh = blockIdx.y;
  int b = bh >> 4, h = bh & 15;
  int tid = threadIdx.x, lane = tid & 63, w = tid >> 6;
  int r16 = lane & 15, hi = lane >> 4;
  int rowbase = blockIdx.x * 128 + w * 32;
  const u16* qb = Q + ((size_t)bh * 4096 + rowbase) * 64;
  const u16* kb = klmb + (size_t)bh * 4096;
  const u16* wtb = WT + (size_t)bh * 4096;
  u16* eb = &Elds[w][0];
  f32x4 z4 = {0.f, 0.f, 0.f, 0.f};

  bf16x8 afr[2][2];
#pragma unroll
  for (int mi = 0; mi < 2; ++mi)
#pragma unroll
    for (int kk = 0; kk < 2; ++kk)
      afr[mi][kk] = *(const bf16x8*)(qb + (mi * 16 + r16) * 64 + kk * 32 + hi * 8);

  float rs[2][4] = {};
  for (int cf = 0; cf < 4; ++cf) {
    f32x4 S[2] = {z4, z4};
#pragma unroll
    for (int kk = 0; kk < 2; ++kk) {
      bf16x8 bfr = *(const bf16x8*)(kb + (cf * 16 + r16) * 64 + kk * 32 + hi * 8);
#pragma unroll
      for (int mi = 0; mi < 2; ++mi) S[mi] = MFMA16(afr[mi][kk], bfr, S[mi]);
    }
#pragma unroll
    for (int mi = 0; mi < 2; ++mi)
#pragma unroll
      for (int r = 0; r < 4; ++r) {
        float e = __expf(S[mi][r]);
        rs[mi][r] += e;
        int row = mi * 16 + hi * 4 + r;
        int key = cf * 16 + r16;
        *(u16*)((char*)eb + row * 128 + ((key * 2) ^ ((row & 7) << 4))) = f2bfu(e);
      }
  }
#pragma unroll
  for (int mi = 0; mi < 2; ++mi)
#pragma unroll
    for (int r = 0; r < 4; ++r) {
      float v = rs[mi][r];
      v += __shfl_xor(v, 1); v += __shfl_xor(v, 2);
      v += __shfl_xor(v, 4); v += __shfl_xor(v, 8);
      rs[mi][r] = v;
    }
  __syncthreads();

  f32x4 O[2][4];
#pragma unroll
  for (int mi = 0; mi < 2; ++mi)
#pragma unroll
    for (int df = 0; df < 4; ++df) O[mi][df] = z4;
  for (int ks = 0; ks < 2; ++ks) {
    bf16x8 ea[2];
#pragma unroll
    for (int mi = 0; mi < 2; ++mi) {
      int row = mi * 16 + r16;
      ea[mi] = *(const bf16x8*)((char*)eb + row * 128 + (((ks * 32 + hi * 8) * 2) ^ ((row & 7) << 4)));
    }
#pragma unroll
    for (int df = 0; df < 4; ++df) {
      bf16x8 wfr = *(const bf16x8*)(wtb + (df * 16 + r16) * 64 + ks * 32 + hi * 8);
#pragma unroll
      for (int mi = 0; mi < 2; ++mi) O[mi][df] = MFMA16(ea[mi], wfr, O[mi][df]);
    }
  }
#pragma unroll
  for (int mi = 0; mi < 2; ++mi)
#pragma unroll
    for (int df = 0; df < 4; ++df)
#pragma unroll
      for (int r = 0; r < 4; ++r) {
        int row = mi * 16 + hi * 4 + r;
        int n = rowbase + row;
        int col = h * 64 + df * 16 + r16;
        float val = O[mi][df][r] / rs[mi][r];
        AO[((size_t)b * 4096 + n) * 1024 + col] = f2bfu(val);
      }
}

// ---------------------------------------------------------------- launcher
extern "C" void kernel_launch(void* const* d_in, const int* in_sizes, int n_in,
                              void* d_out, int out_size, void* d_ws, size_t ws_size,
                              hipStream_t stream) {
  (void)in_sizes; (void)n_in; (void)out_size; (void)ws_size;
  const float* x       = (const float*)d_in[0];
  const float* ln_w    = (const float*)d_in[1];
  const float* ln_b    = (const float*)d_in[2];
  const float* qkv_w   = (const float*)d_in[3];
  const float* qkv_b   = (const float*)d_in[4];
  const float* gamma_w = (const float*)d_in[5];
  const float* gamma_b = (const float*)d_in[6];
  const float* proj_w  = (const float*)d_in[7];
  const float* proj_b  = (const float*)d_in[8];

  char* ws = (char*)d_ws;
  u16* XN     = (u16*)(ws + 0);           // 33.5 MB (xn; later Upart overlay; later attn_out)
  u16* Qb     = (u16*)(ws + 33554432);
  u16* Kb     = (u16*)(ws + 67108864);    // k; later y1
  u16* Vb     = (u16*)(ws + 100663296);   // V^T layout: per bh [64][4096]
  u16* QKVW   = (u16*)(ws + 134217728);
  u16* GW     = (u16*)(ws + 140509184);
  u16* PW     = (u16*)(ws + 142606336);
  float* QLMF = (float*)(ws + 144703488);
  float* KLMF = (float*)(ws + 145752064);
  u16* QLMB   = (u16*)(ws + 146800640);
  u16* KLMB   = (u16*)(ws + 147324928);
  float* RSP  = (float*)(ws + 147849216);
  u16* WTb    = (u16*)(ws + 148373504);
  float* UP   = (float*)XN;               // overlay: xn dead after qkv GEMM

  ln_kernel<<<16384, 256, 0, stream>>>(x, ln_w, ln_b, XN);
  cvt3_kernel<<<2048, 256, 0, stream>>>(qkv_w, QKVW, 3145728,
                                        gamma_w, GW, 1048576,
                                        proj_w, PW, 1048576);
  gemm_bt<2><<<dim3(12, 64), 512, 0, stream>>>(XN, QKVW, qkv_b, nullptr, nullptr,
                                               Qb, Kb, Vb, 16384, 3072, 1024);
  landmark_kernel<<<dim3(4096, 2), 64, 0, stream>>>(Qb, Kb, QLMF, QLMB, KLMF, KLMB);
  attn3_pv_kernel<<<dim3(8, 64), 256, 0, stream>>>(QLMB, Kb, Vb, UP, RSP);
  combine_ns_kernel<<<64, 512, 0, stream>>>(UP, RSP, QLMF, KLMF, WTb);
  attn1_out_kernel<<<dim3(32, 64), 256, 0, stream>>>(Qb, KLMB, WTb, XN);
  gemm_bt<0><<<dim3(4, 64), 512, 0, stream>>>(XN, GW, gamma_b, nullptr, Kb,
                                              nullptr, nullptr, nullptr, 16384, 1024, 1024);
  gemm_bt<1><<<dim3(4, 64), 512, 0, stream>>>(Kb, PW, proj_b, (float*)d_out, nullptr,
                                              nullptr, nullptr, nullptr, 16384, 1024, 1024);
}

// Round 5
// 370.745 us; speedup vs baseline: 1.5619x; 1.5619x over previous
//
#include <hip/hip_runtime.h>
#include <stdint.h>

typedef unsigned short u16;
typedef short bf16x8 __attribute__((ext_vector_type(8)));
typedef float f32x4 __attribute__((ext_vector_type(4)));

#define MFMA16(a, b, c) __builtin_amdgcn_mfma_f32_16x16x32_bf16((a), (b), (c), 0, 0, 0)

static __device__ __forceinline__ float bfu2f(u16 u) {
  union { unsigned int i; float f; } z; z.i = ((unsigned int)u) << 16; return z.f;
}
static __device__ __forceinline__ u16 f2bfu(float f) {
  union { float f; unsigned int i; } z; z.f = f;
  unsigned int i = z.i;
  return (u16)((i + 0x7fffu + ((i >> 16) & 1u)) >> 16);
}

__device__ __forceinline__ void gload_lds16(const void* g, void* l) {
  __builtin_amdgcn_global_load_lds((const __attribute__((address_space(1))) void*)g,
                                   (__attribute__((address_space(3))) void*)l, 16, 0, 0);
}

// ---------------------------------------------------------------- LayerNorm
__global__ __launch_bounds__(256) void ln_kernel(
    const float* __restrict__ x, const float* __restrict__ w,
    const float* __restrict__ b, u16* __restrict__ xn) {
  int row = blockIdx.x;
  int t = threadIdx.x;
  const float4* xr = (const float4*)(x + (size_t)row * 1024);
  float4 v = xr[t];
  float s = v.x + v.y + v.z + v.w;
  float ss = v.x * v.x + v.y * v.y + v.z * v.z + v.w * v.w;
#pragma unroll
  for (int m = 1; m < 64; m <<= 1) { s += __shfl_xor(s, m); ss += __shfl_xor(ss, m); }
  __shared__ float sb[4], ssb[4];
  int lane = t & 63, wvi = t >> 6;
  if (lane == 0) { sb[wvi] = s; ssb[wvi] = ss; }
  __syncthreads();
  s = sb[0] + sb[1] + sb[2] + sb[3];
  ss = ssb[0] + ssb[1] + ssb[2] + ssb[3];
  float mu = s * (1.0f / 1024.0f);
  float var = ss * (1.0f / 1024.0f) - mu * mu;
  float rstd = rsqrtf(var + 1e-5f);
  float4 wv4 = ((const float4*)w)[t];
  float4 bv4 = ((const float4*)b)[t];
  ushort4 o;
  o.x = f2bfu((v.x - mu) * rstd * wv4.x + bv4.x);
  o.y = f2bfu((v.y - mu) * rstd * wv4.y + bv4.y);
  o.z = f2bfu((v.z - mu) * rstd * wv4.z + bv4.z);
  o.w = f2bfu((v.w - mu) * rstd * wv4.w + bv4.w);
  ((ushort4*)xn)[(size_t)row * 256 + t] = o;
}

// ------------------------------------------------------------- f32 -> bf16
__global__ void cvt3_kernel(const float* __restrict__ a, u16* __restrict__ oa, int na,
                            const float* __restrict__ b, u16* __restrict__ ob, int nb,
                            const float* __restrict__ c, u16* __restrict__ oc, int nc) {
  int total = (na + nb + nc) >> 2;
  for (int i = blockIdx.x * blockDim.x + threadIdx.x; i < total; i += gridDim.x * blockDim.x) {
    int j = i << 2;
    const float* s; u16* d; int off;
    if (j < na) { s = a; d = oa; off = j; }
    else if (j < na + nb) { s = b; d = ob; off = j - na; }
    else { s = c; d = oc; off = j - na - nb; }
    float4 v = *(const float4*)(s + off);
    ushort4 o;
    o.x = f2bfu(v.x); o.y = f2bfu(v.y); o.z = f2bfu(v.z); o.w = f2bfu(v.w);
    *(ushort4*)(d + off) = o;
  }
}

// --------------------------------------------------- GEMM  C = A @ Bw^T + bias
// m201-style 8-phase schedule: BM=BN=256, BK=64, 8 waves (2Mx4N), per-wave
// 128x64 output. 2 double-buffered LDS K-tiles; 4 quadrant-phases per K-tile;
// counted vmcnt(6) once per K-tile. Bijective XCD swizzle on flattened block
// index (requires gridDim.x*gridDim.y % 8 == 0 -- true for all our grids).
// MODE 0: bf16 out; MODE 1: f32 out; MODE 2: qkv scatter (V stored transposed).
template <int MODE>
__global__ __launch_bounds__(512, 2) void gemm_bt(
    const u16* __restrict__ A, const u16* __restrict__ Bw,
    const float* __restrict__ bias,
    float* __restrict__ Cf, u16* __restrict__ Cb,
    u16* __restrict__ Qo, u16* __restrict__ Ko, u16* __restrict__ Vo,
    int M, int N, int K) {
  __shared__ __attribute__((aligned(16))) u16 As[2][16384];  // [256][64] bf16
  __shared__ __attribute__((aligned(16))) u16 Bs[2][16384];  // [256][64] bf16
  int tid = threadIdx.x;
  int lane = tid & 63;
  int w = tid >> 6;            // 0..7
  int wr = w >> 2, wc = w & 3; // wave grid 2 (M) x 4 (N)
  int r16 = lane & 15, hi = lane >> 4;
  int l8 = lane >> 3, li = lane & 7;

  // XCD-aware bijective swizzle (nwg % 8 == 0).
  int nwg = gridDim.x * gridDim.y;
  int flat = blockIdx.y * gridDim.x + blockIdx.x;
  int q8 = nwg >> 3;
  int swz = (flat & 7) * q8 + (flat >> 3);
  int bx = swz % gridDim.x, by = swz / gridDim.x;

  const char* Abase = (const char*)(A + (size_t)by * 256 * K);
  const char* Bbase = (const char*)(Bw + (size_t)bx * 256 * K);
  size_t rowbytes = (size_t)K * 2;
  int colsw = (li ^ l8) << 4;  // pre-swizzled source 16B slot in 128B window
  int nkt = K >> 6;            // assumed >= 2

  f32x4 z4 = {0.f, 0.f, 0.f, 0.f};
  f32x4 acc[8][4];
#pragma unroll
  for (int m = 0; m < 8; ++m)
#pragma unroll
    for (int n = 0; n < 4; ++n) acc[m][n] = z4;

  // One 8KB stage block: 64 LDS rows; wave w covers rows r0+w*8+l8.
#define SG_A(buf, t, r0)                                                      \
  gload_lds16(Abase + (size_t)((r0) + w * 8 + l8) * rowbytes + ((t) << 7) +   \
                  colsw,                                                      \
              (char*)As[buf] + ((r0) + w * 8) * 128)
#define SG_B(buf, t, r0)                                                      \
  gload_lds16(Bbase + (size_t)((r0) + w * 8 + l8) * rowbytes + ((t) << 7) +   \
                  colsw,                                                      \
              (char*)Bs[buf] + ((r0) + w * 8) * 128)

  // Prologue: tile0 full (8 issues) + tile1 first 6 issues.
  SG_A(0, 0, 0); SG_A(0, 0, 64); SG_A(0, 0, 128); SG_A(0, 0, 192);
  SG_B(0, 0, 0); SG_B(0, 0, 64); SG_B(0, 0, 128); SG_B(0, 0, 192);
  SG_A(1, 1, 0); SG_A(1, 1, 128); SG_B(1, 1, 0); SG_B(1, 1, 64);
  SG_A(1, 1, 64); SG_A(1, 1, 192);
  asm volatile("s_waitcnt vmcnt(6)" ::: "memory");
  __builtin_amdgcn_s_barrier();
  __builtin_amdgcn_sched_barrier(0);

  int buf = 0;
  bf16x8 af[4][2], bfr[4][2];

#define LDA(mh)                                                               \
  _Pragma("unroll") for (int m = 0; m < 4; ++m) {                             \
    int row = wr * 128 + (mh) * 64 + m * 16 + r16;                            \
    int sw = (row & 7) << 4;                                                  \
    _Pragma("unroll") for (int kk = 0; kk < 2; ++kk)                          \
        af[m][kk] = *(const bf16x8*)(ab + row * 128 +                         \
                                     (((kk << 6) | (hi << 4)) ^ sw));         \
  }
#define LDB(nh)                                                               \
  _Pragma("unroll") for (int n = 0; n < 2; ++n) {                             \
    int row = wc * 64 + (nh) * 32 + n * 16 + r16;                             \
    int sw = (row & 7) << 4;                                                  \
    _Pragma("unroll") for (int kk = 0; kk < 2; ++kk)                          \
        bfr[(nh) * 2 + n][kk] = *(const bf16x8*)(ab2 + row * 128 +            \
                                     (((kk << 6) | (hi << 4)) ^ sw));         \
  }
#define MM(mh, nh)                                                            \
  __builtin_amdgcn_s_setprio(1);                                              \
  _Pragma("unroll") for (int kk = 0; kk < 2; ++kk)                            \
      _Pragma("unroll") for (int m = 0; m < 4; ++m)                           \
          _Pragma("unroll") for (int n = 0; n < 2; ++n)                       \
              acc[(mh) * 4 + m][(nh) * 2 + n] =                               \
      MFMA16(af[m][kk], bfr[(nh) * 2 + n][kk], acc[(mh) * 4 + m][(nh) * 2 + n]); \
  __builtin_amdgcn_s_setprio(0)

#define BAR1                                                                  \
  __builtin_amdgcn_s_barrier();                                               \
  __builtin_amdgcn_sched_barrier(0)
#define BAR2                                                                  \
  __builtin_amdgcn_sched_barrier(0);                                          \
  __builtin_amdgcn_s_barrier();                                               \
  __builtin_amdgcn_sched_barrier(0)

  for (int t = 0; t < nkt; ++t) {
    const char* ab = (const char*)As[buf];
    const char* ab2 = (const char*)Bs[buf];
    bool s1 = (t + 1 < nkt), s2 = (t + 2 < nkt);
    // ---- phase q0: quadrant (mh0, nh0)
    LDA(0);
    LDB(0);
    if (s1) { SG_B(buf ^ 1, t + 1, 128); SG_B(buf ^ 1, t + 1, 192); }
    BAR1;
    MM(0, 0);
    BAR2;
    // ---- phase q1: (mh0, nh1)
    LDB(1);
    if (s2) { SG_A(buf, t + 2, 0); SG_A(buf, t + 2, 128); }
    BAR1;
    MM(0, 1);
    BAR2;
    // ---- phase q2: (mh1, nh0)
    LDA(1);
    if (s2) { SG_B(buf, t + 2, 0); SG_B(buf, t + 2, 64); }
    BAR1;
    MM(1, 0);
    BAR2;
    // ---- phase q3: (mh1, nh1)  (frags already in regs)
    if (s2) { SG_A(buf, t + 2, 64); SG_A(buf, t + 2, 192); }
    BAR1;
    MM(1, 1);
    __builtin_amdgcn_sched_barrier(0);
    if (s2) {
      asm volatile("s_waitcnt vmcnt(6)" ::: "memory");
    } else {
      asm volatile("s_waitcnt vmcnt(0)" ::: "memory");
    }
    __builtin_amdgcn_s_barrier();
    __builtin_amdgcn_sched_barrier(0);
    buf ^= 1;
  }
#undef SG_A
#undef SG_B
#undef LDA
#undef LDB
#undef MM
#undef BAR1
#undef BAR2

#pragma unroll
  for (int m = 0; m < 8; ++m)
#pragma unroll
    for (int n = 0; n < 4; ++n) {
      int row0 = by * 256 + wr * 128 + m * 16 + hi * 4;
      int col = bx * 256 + wc * 64 + n * 16 + r16;
      if (MODE == 2) {
        int jt = col >> 10;
        int h = (col >> 6) & 15, dh = col & 63;
        int bb = row0 >> 12, nt0 = row0 & 4095;
        float bcol = bias[col];
        if (jt == 2) {
          // V stored transposed: VT[bh][dh][n] -> vectorized ushort4 store.
          ushort4 o;
          o.x = f2bfu(acc[m][n][0] + bcol);
          o.y = f2bfu(acc[m][n][1] + bcol);
          o.z = f2bfu(acc[m][n][2] + bcol);
          o.w = f2bfu(acc[m][n][3] + bcol);
          *(ushort4*)&Vo[(((size_t)bb * 16 + h) * 64 + dh) * 4096 + nt0] = o;
        } else {
          u16* dst = (jt == 0) ? Qo : Ko;
#pragma unroll
          for (int r = 0; r < 4; ++r)
            dst[(((size_t)bb * 16 + h) * 4096 + nt0 + r) * 64 + dh] =
                f2bfu(acc[m][n][r] + bcol);
        }
      } else {
        float bcol = bias[col];
#pragma unroll
        for (int r = 0; r < 4; ++r) {
          int row = row0 + r;
          float val = acc[m][n][r] + bcol;
          if (MODE == 0) Cb[(size_t)row * N + col] = f2bfu(val);
          else           Cf[(size_t)row * N + col] = val;
        }
      }
    }
}

// ------------------------------------------------------------- landmarks
__global__ __launch_bounds__(64) void landmark_kernel(
    const u16* __restrict__ Q, const u16* __restrict__ K,
    float* __restrict__ qlmf, u16* __restrict__ qlmb,
    float* __restrict__ klmf, u16* __restrict__ klmb) {
  int bm = blockIdx.x;  // bh*64 + m
  int bh = bm >> 6, m = bm & 63;
  int d = threadIdx.x;
  const u16* src = blockIdx.y ? K : Q;
  const u16* p = src + (((size_t)bh * 4096) + m * 64) * 64 + d;
  float s = 0.f;
#pragma unroll 8
  for (int r = 0; r < 64; ++r) s += bfu2f(p[(size_t)r * 64]);
  float val = s * (0.25f / 64.0f);  // mean * SCALE
  size_t o = (size_t)bh * 4096 + m * 64 + d;
  if (blockIdx.y) { klmf[o] = val; klmb[o] = f2bfu(val); }
  else            { qlmf[o] = val; qlmb[o] = f2bfu(val); }
}

// ---------------------- attn3 scores + exp + (E @ V^T-layout) partials
__global__ __launch_bounds__(256) void attn3_pv_kernel(
    const u16* __restrict__ qlmb, const u16* __restrict__ Kmat,
    const u16* __restrict__ Vt, float* __restrict__ Upart,
    float* __restrict__ rspart) {
  __shared__ __attribute__((aligned(16))) u16 Elds[4][8192];  // per-wave 64x128 bf16, swizzled
  int chunk = blockIdx.x, bh = blockIdx.y;
  int tid = threadIdx.x, lane = tid & 63, w = tid >> 6;
  int r16 = lane & 15, hi = lane >> 4;
  int keybase = chunk * 512 + w * 128;
  const u16* kb = Kmat + ((size_t)bh * 4096 + keybase) * 64;
  const u16* vtb = Vt + (size_t)bh * 262144;  // V^T: [64][4096] per bh
  const u16* qb = qlmb + (size_t)bh * 4096;
  u16* eb = &Elds[w][0];
  f32x4 z4 = {0.f, 0.f, 0.f, 0.f};

  bf16x8 afr[4][2];
#pragma unroll
  for (int m = 0; m < 4; ++m)
#pragma unroll
    for (int kk = 0; kk < 2; ++kk)
      afr[m][kk] = *(const bf16x8*)(qb + (m * 16 + r16) * 64 + kk * 32 + hi * 8);

  float rs[4][4] = {};
  for (int cf = 0; cf < 8; ++cf) {
    f32x4 S[4] = {z4, z4, z4, z4};
#pragma unroll
    for (int kk = 0; kk < 2; ++kk) {
      bf16x8 bfr = *(const bf16x8*)(kb + (size_t)(cf * 16 + r16) * 64 + kk * 32 + hi * 8);
#pragma unroll
      for (int m = 0; m < 4; ++m) S[m] = MFMA16(afr[m][kk], bfr, S[m]);
    }
#pragma unroll
    for (int m = 0; m < 4; ++m)
#pragma unroll
      for (int r = 0; r < 4; ++r) {
        float e = __expf(S[m][r]);  // max-free: logits are O(0.1) by construction
        rs[m][r] += e;
        int row = m * 16 + hi * 4 + r;
        int key = cf * 16 + r16;
        *(u16*)((char*)eb + row * 256 + ((key * 2) ^ ((row & 7) << 4))) = f2bfu(e);
      }
  }
#pragma unroll
  for (int m = 0; m < 4; ++m)
#pragma unroll
    for (int r = 0; r < 4; ++r) {
      float v = rs[m][r];
      v += __shfl_xor(v, 1); v += __shfl_xor(v, 2);
      v += __shfl_xor(v, 4); v += __shfl_xor(v, 8);
      rs[m][r] = v;
    }
  if (r16 == 0) {
    float* rp = rspart + (((size_t)bh * 8 + chunk) * 4 + w) * 64;
#pragma unroll
    for (int m = 0; m < 4; ++m)
#pragma unroll
      for (int r = 0; r < 4; ++r) rp[m * 16 + hi * 4 + r] = rs[m][r];
  }
  __syncthreads();

  f32x4 U[4][4];
#pragma unroll
  for (int m = 0; m < 4; ++m)
#pragma unroll
    for (int df = 0; df < 4; ++df) U[m][df] = z4;
  for (int ks = 0; ks < 4; ++ks) {
    bf16x8 ea[4];
#pragma unroll
    for (int m = 0; m < 4; ++m) {
      int row = m * 16 + r16;
      ea[m] = *(const bf16x8*)((char*)eb + row * 256 + (((ks * 32 + hi * 8) * 2) ^ ((row & 7) << 4)));
    }
#pragma unroll
    for (int df = 0; df < 4; ++df) {
      bf16x8 vb8 = *(const bf16x8*)(vtb + (size_t)(df * 16 + r16) * 4096 +
                                    keybase + ks * 32 + hi * 8);
#pragma unroll
      for (int m = 0; m < 4; ++m) U[m][df] = MFMA16(ea[m], vb8, U[m][df]);
    }
  }
  float* up = Upart + (((size_t)bh * 8 + chunk) * 4 + w) * 4096;
#pragma unroll
  for (int m = 0; m < 4; ++m)
#pragma unroll
    for (int df = 0; df < 4; ++df)
#pragma unroll
      for (int r = 0; r < 4; ++r)
        up[(m * 16 + hi * 4 + r) * 64 + df * 16 + r16] = U[m][df][r];
}

// --------------- reduce partials -> Tmf[bh][64][64] = (attn3 @ v) row-normalized
__global__ __launch_bounds__(256) void reduce_t_kernel(
    const float* __restrict__ Upart, const float* __restrict__ rspart,
    float* __restrict__ Tmf) {
  int bh = blockIdx.y;
  int tid = threadIdx.x;
  __shared__ float rsum[64];
  if (tid < 64) {
    float s = 0.f;
    const float* rp = rspart + (size_t)bh * 2048 + tid;
#pragma unroll 8
    for (int p = 0; p < 32; ++p) s += rp[p * 64];
    rsum[tid] = s;
  }
  __syncthreads();
  int idx4 = blockIdx.x * 256 + tid;  // gridDim.x = 4 -> 1024 float4 per bh
  const float4* up = (const float4*)(Upart + (size_t)bh * 131072) + idx4;
  float4 s = {0.f, 0.f, 0.f, 0.f};
#pragma unroll 8
  for (int p = 0; p < 32; ++p) {
    float4 v = up[p * 1024];
    s.x += v.x; s.y += v.y; s.z += v.z; s.w += v.w;
  }
  float inv = 1.0f / rsum[idx4 >> 4];
  s.x *= inv; s.y *= inv; s.z *= inv; s.w *= inv;
  ((float4*)(Tmf + (size_t)bh * 4096))[idx4] = s;
}

// ------------- attn2 softmax + Newton-Schulz (fp32) + W = A2inv @ T -> WT bf16
__device__ __forceinline__ void mm64(const float (*AT)[68], const float (*Bm)[68],
                                     float (*C)[68], float (*CT)[68],
                                     float alpha, int tid) {
  int tr = (tid >> 4) << 2;
  int tc = (tid & 15) << 2;
  float acc[4][4] = {};
#pragma unroll 4
  for (int k = 0; k < 64; ++k) {
    float4 av = *(const float4*)&AT[k][tr];
    float4 bv = *(const float4*)&Bm[k][tc];
    float aa[4] = {av.x, av.y, av.z, av.w};
    float bb[4] = {bv.x, bv.y, bv.z, bv.w};
#pragma unroll
    for (int i = 0; i < 4; ++i)
#pragma unroll
      for (int j = 0; j < 4; ++j) acc[i][j] = fmaf(aa[i], bb[j], acc[i][j]);
  }
#pragma unroll
  for (int i = 0; i < 4; ++i)
#pragma unroll
    for (int j = 0; j < 4; ++j) {
      float vv = acc[i][j] * alpha;
      C[tr + i][tc + j] = vv;
      if (CT) CT[tc + j][tr + i] = vv;
    }
}

__global__ __launch_bounds__(256) void combine_ns_kernel(
    const float* __restrict__ Tmf, const float* __restrict__ qlmf,
    const float* __restrict__ klmf, u16* __restrict__ WT) {
  __shared__ __attribute__((aligned(16))) float A2T[64][68];
  __shared__ __attribute__((aligned(16))) float Vv[64][68];
  __shared__ __attribute__((aligned(16))) float VT[64][68];
  __shared__ __attribute__((aligned(16))) float KV[64][68];
  __shared__ __attribute__((aligned(16))) float KVT[64][68];
  __shared__ __attribute__((aligned(16))) float T2[64][68];
  __shared__ __attribute__((aligned(16))) float T4[64][68];
  __shared__ __attribute__((aligned(16))) float Tm[64][68];
  __shared__ float redbuf[64];
  __shared__ float v0s, scal;
  int bh = blockIdx.x, tid = threadIdx.x;

  // Load Tm (coalesced) and transposed landmark matrices.
  for (int idx = tid; idx < 1024; idx += 256) {
    float4 v = ((const float4*)(Tmf + (size_t)bh * 4096))[idx];
    int r = idx >> 4, c0 = (idx & 15) << 2;
    *(float4*)&Tm[r][c0] = v;
  }
  for (int idx = tid; idx < 4096; idx += 256) {
    int r = idx >> 6, c = idx & 63;
    Vv[c][r] = qlmf[(size_t)bh * 4096 + idx];  // qlm^T
    VT[c][r] = klmf[(size_t)bh * 4096 + idx];  // klm^T
  }
  __syncthreads();
  mm64(&Vv[0], &VT[0], &T2[0], nullptr, 1.0f, tid);  // S2 = qlm @ klm^T
  __syncthreads();
  if (tid < 64) {  // softmax row tid (fp32)
    float mx = -1e30f;
    for (int c2 = 0; c2 < 64; ++c2) mx = fmaxf(mx, T2[tid][c2]);
    float s = 0.f;
    for (int c2 = 0; c2 < 64; ++c2) { float e = __expf(T2[tid][c2] - mx); T2[tid][c2] = e; s += e; }
    float inv = 1.f / s;
    for (int c2 = 0; c2 < 64; ++c2) { float p = T2[tid][c2] * inv; T2[tid][c2] = p; A2T[c2][tid] = p; }
  }
  __syncthreads();
  if (tid < 64) {  // column sums of |A2|
    float cs = 0.f;
    for (int r2 = 0; r2 < 64; ++r2) cs += fabsf(T2[r2][tid]);
    redbuf[tid] = cs;
  }
  __syncthreads();
  if (tid == 0) {
    float v0 = 0.f;
    for (int c2 = 0; c2 < 64; ++c2) v0 = fmaxf(v0, redbuf[c2]);
    v0s = v0;
  }
  __syncthreads();
  if (tid < 64) {  // row sums
    float rs2 = 0.f;
    for (int c2 = 0; c2 < 64; ++c2) rs2 += fabsf(T2[tid][c2]);
    redbuf[tid] = rs2;
  }
  __syncthreads();
  if (tid == 0) {
    float vi = 0.f;
    for (int r2 = 0; r2 < 64; ++r2) vi = fmaxf(vi, redbuf[r2]);
    scal = 1.0f / (v0s * vi);
  }
  __syncthreads();
  for (int idx = tid; idx < 4096; idx += 256) {
    int r = idx >> 6, c = idx & 63;
    Vv[r][c] = A2T[r][c] * scal;  // V = A2^T / (V0*VI)
    VT[r][c] = T2[r][c] * scal;   // V^T
  }
  __syncthreads();
#pragma unroll 1
  for (int it = 0; it < 6; ++it) {
    mm64(&A2T[0], &Vv[0], &KV[0], &KVT[0], 1.0f, tid);  // KV = A2 @ V
    __syncthreads();
    for (int idx = tid; idx < 4096; idx += 256) {
      int r = idx >> 6, c = idx & 63;
      T2[r][c] = ((r == c) ? 7.0f : 0.0f) - KV[r][c];
    }
    __syncthreads();
    mm64(&KVT[0], &T2[0], &T4[0], nullptr, 1.0f, tid);  // KV @ (7I - KV)
    __syncthreads();
    for (int idx = tid; idx < 4096; idx += 256) {
      int r = idx >> 6, c = idx & 63;
      T2[r][c] = ((r == c) ? 15.0f : 0.0f) - T4[r][c];
    }
    __syncthreads();
    mm64(&KVT[0], &T2[0], &T4[0], nullptr, 1.0f, tid);  // KV @ (15I - ...)
    __syncthreads();
    for (int idx = tid; idx < 4096; idx += 256) {
      int r = idx >> 6, c = idx & 63;
      T2[r][c] = ((r == c) ? 13.0f : 0.0f) - T4[r][c];
    }
    __syncthreads();
    mm64(&VT[0], &T2[0], &T4[0], nullptr, 0.25f, tid);  // Vnew = 0.25 V @ (13I - ...)
    __syncthreads();
    for (int idx = tid; idx < 4096; idx += 256) {
      int r = idx >> 6, c = idx & 63;
      float vvv = T4[r][c];
      Vv[r][c] = vvv; VT[c][r] = vvv;
    }
    __syncthreads();
  }
  mm64(&VT[0], &Tm[0], &T2[0], nullptr, 1.0f, tid);  // W = A2inv @ T
  __syncthreads();
  for (int idx = tid; idx < 4096; idx += 256) {
    int r = idx >> 6, c = idx & 63;
    WT[(size_t)bh * 4096 + c * 64 + r] = f2bfu(T2[r][c]);  // store W^T bf16
  }
}

// ------------------- final: softmax(q @ klm^T) @ W  ->  attn_out (B,N,C) bf16
__global__ __launch_bounds__(256) void attn1_out_kernel(
    const u16* __restrict__ Q, const u16* __restrict__ klmb,
    const u16* __restrict__ WT, u16* __restrict__ AO) {
  __shared__ __attribute__((aligned(16))) u16 Elds[4][2048];  // per-wave 32x64 bf16
  int bh = blockIdx.y;
  int b = bh >> 4, h = bh & 15;
  int tid = threadIdx.x, lane = tid & 63, w = tid >> 6;
  int r16 = lane & 15, hi = lane >> 4;
  int rowbase = blockIdx.x * 128 + w * 32;
  const u16* qb = Q + ((size_t)bh * 4096 + rowbase) * 64;
  const u16* kb = klmb + (size_t)bh * 4096;
  const u16* wtb = WT + (size_t)bh * 4096;
  u16* eb = &Elds[w][0];
  f32x4 z4 = {0.f, 0.f, 0.f, 0.f};

  bf16x8 afr[2][2];
#pragma unroll
  for (int mi = 0; mi < 2; ++mi)
#pragma unroll
    for (int kk = 0; kk < 2; ++kk)
      afr[mi][kk] = *(const bf16x8*)(qb + (mi * 16 + r16) * 64 + kk * 32 + hi * 8);

  float rs[2][4] = {};
  for (int cf = 0; cf < 4; ++cf) {
    f32x4 S[2] = {z4, z4};
#pragma unroll
    for (int kk = 0; kk < 2; ++kk) {
      bf16x8 bfr = *(const bf16x8*)(kb + (cf * 16 + r16) * 64 + kk * 32 + hi * 8);
#pragma unroll
      for (int mi = 0; mi < 2; ++mi) S[mi] = MFMA16(afr[mi][kk], bfr, S[mi]);
    }
#pragma unroll
    for (int mi = 0; mi < 2; ++mi)
#pragma unroll
      for (int r = 0; r < 4; ++r) {
        float e = __expf(S[mi][r]);
        rs[mi][r] += e;
        int row = mi * 16 + hi * 4 + r;
        int key = cf * 16 + r16;
        *(u16*)((char*)eb + row * 128 + ((key * 2) ^ ((row & 7) << 4))) = f2bfu(e);
      }
  }
#pragma unroll
  for (int mi = 0; mi < 2; ++mi)
#pragma unroll
    for (int r = 0; r < 4; ++r) {
      float v = rs[mi][r];
      v += __shfl_xor(v, 1); v += __shfl_xor(v, 2);
      v += __shfl_xor(v, 4); v += __shfl_xor(v, 8);
      rs[mi][r] = v;
    }
  __syncthreads();

  f32x4 O[2][4];
#pragma unroll
  for (int mi = 0; mi < 2; ++mi)
#pragma unroll
    for (int df = 0; df < 4; ++df) O[mi][df] = z4;
  for (int ks = 0; ks < 2; ++ks) {
    bf16x8 ea[2];
#pragma unroll
    for (int mi = 0; mi < 2; ++mi) {
      int row = mi * 16 + r16;
      ea[mi] = *(const bf16x8*)((char*)eb + row * 128 + (((ks * 32 + hi * 8) * 2) ^ ((row & 7) << 4)));
    }
#pragma unroll
    for (int df = 0; df < 4; ++df) {
      bf16x8 wfr = *(const bf16x8*)(wtb + (df * 16 + r16) * 64 + ks * 32 + hi * 8);
#pragma unroll
      for (int mi = 0; mi < 2; ++mi) O[mi][df] = MFMA16(ea[mi], wfr, O[mi][df]);
    }
  }
#pragma unroll
  for (int mi = 0; mi < 2; ++mi)
#pragma unroll
    for (int df = 0; df < 4; ++df)
#pragma unroll
      for (int r = 0; r < 4; ++r) {
        int row = mi * 16 + hi * 4 + r;
        int n = rowbase + row;
        int col = h * 64 + df * 16 + r16;
        float val = O[mi][df][r] / rs[mi][r];
        AO[((size_t)b * 4096 + n) * 1024 + col] = f2bfu(val);
      }
}

// ---------------------------------------------------------------- launcher
extern "C" void kernel_launch(void* const* d_in, const int* in_sizes, int n_in,
                              void* d_out, int out_size, void* d_ws, size_t ws_size,
                              hipStream_t stream) {
  (void)in_sizes; (void)n_in; (void)out_size; (void)ws_size;
  const float* x       = (const float*)d_in[0];
  const float* ln_w    = (const float*)d_in[1];
  const float* ln_b    = (const float*)d_in[2];
  const float* qkv_w   = (const float*)d_in[3];
  const float* qkv_b   = (const float*)d_in[4];
  const float* gamma_w = (const float*)d_in[5];
  const float* gamma_b = (const float*)d_in[6];
  const float* proj_w  = (const float*)d_in[7];
  const float* proj_b  = (const float*)d_in[8];

  char* ws = (char*)d_ws;
  u16* XN     = (u16*)(ws + 0);           // 33.5 MB (xn; later Upart overlay; later attn_out)
  u16* Qb     = (u16*)(ws + 33554432);
  u16* Kb     = (u16*)(ws + 67108864);    // k; Tmf overlay after attn3; later y1
  u16* Vb     = (u16*)(ws + 100663296);   // V^T layout: per bh [64][4096]
  u16* QKVW   = (u16*)(ws + 134217728);
  u16* GW     = (u16*)(ws + 140509184);
  u16* PW     = (u16*)(ws + 142606336);
  float* QLMF = (float*)(ws + 144703488);
  float* KLMF = (float*)(ws + 145752064);
  u16* QLMB   = (u16*)(ws + 146800640);
  u16* KLMB   = (u16*)(ws + 147324928);
  float* RSP  = (float*)(ws + 147849216);
  u16* WTb    = (u16*)(ws + 148373504);
  float* UP   = (float*)XN;               // overlay: xn dead after qkv GEMM
  float* TMF  = (float*)Kb;               // overlay: K dead after attn3_pv; y1 written later

  ln_kernel<<<16384, 256, 0, stream>>>(x, ln_w, ln_b, XN);
  cvt3_kernel<<<2048, 256, 0, stream>>>(qkv_w, QKVW, 3145728,
                                        gamma_w, GW, 1048576,
                                        proj_w, PW, 1048576);
  gemm_bt<2><<<dim3(12, 64), 512, 0, stream>>>(XN, QKVW, qkv_b, nullptr, nullptr,
                                               Qb, Kb, Vb, 16384, 3072, 1024);
  landmark_kernel<<<dim3(4096, 2), 64, 0, stream>>>(Qb, Kb, QLMF, QLMB, KLMF, KLMB);
  attn3_pv_kernel<<<dim3(8, 64), 256, 0, stream>>>(QLMB, Kb, Vb, UP, RSP);
  reduce_t_kernel<<<dim3(4, 64), 256, 0, stream>>>(UP, RSP, TMF);
  combine_ns_kernel<<<64, 256, 0, stream>>>(TMF, QLMF, KLMF, WTb);
  attn1_out_kernel<<<dim3(32, 64), 256, 0, stream>>>(Qb, KLMB, WTb, XN);
  gemm_bt<0><<<dim3(4, 64), 512, 0, stream>>>(XN, GW, gamma_b, nullptr, Kb,
                                              nullptr, nullptr, nullptr, 16384, 1024, 1024);
  gemm_bt<1><<<dim3(4, 64), 512, 0, stream>>>(Kb, PW, proj_b, (float*)d_out, nullptr,
                                              nullptr, nullptr, nullptr, 16384, 1024, 1024);
}